// Round 2
// baseline (357.267 us; speedup 1.0000x reference)
//
#include <hip/hip_runtime.h>
#include <math.h>

#define NBINS    15
#define CDIM     1000
#define QDIM     250                 // CDIM / 4
#define HIST_ELEMS (NBINS * CDIM)
#define THREADS  1024
#define NWAVES   (THREADS / 64)      // 16 waves per block
#define SBSTRIDE 256                 // padded per-k stride in sB (q in [0,256))
#define PAD      -1000.0f            // exp(PAD) == 0 exactly -> conf == 0 -> add == 0

__device__ __forceinline__ float waveSum(float v) {
#pragma unroll
    for (int o = 32; o > 0; o >>= 1) v += __shfl_xor(v, o, 64);
    return v;
}

__device__ __forceinline__ void loadRow(float4 (&v)[4], int& label,
                                        const float* __restrict__ logits,
                                        const int* __restrict__ labels,
                                        int r, int lane) {
    const float4* row = (const float4*)(logits + (size_t)r * CDIM);
#pragma unroll
    for (int j = 0; j < 3; ++j) v[j] = row[lane + 64 * j];     // q < 192 < QDIM always
    v[3] = make_float4(PAD, PAD, PAD, PAD);
    if (lane < QDIM - 192) v[3] = row[lane + 192];             // lanes 0..57
    label = labels[r];
}

// sB layout: slot = k*SBSTRIDE + q  (q = lane + 64j, class c = 4q + k).
// Pad lanes (q >= 250) write conf == 0.0 into padding slots [250,256) — harmless,
// never read back. Global D layout: b*CDIM + k*QDIM + q (bijective class map).
__device__ __forceinline__ void computeRow(float4 (&v)[4], int label, int lane,
                                           float* __restrict__ sB,
                                           float* __restrict__ D) {
    float s = 0.0f, m = 0.0f;
#pragma unroll
    for (int j = 0; j < 4; ++j) {
        v[j].x = __expf(v[j].x);
        v[j].y = __expf(v[j].y);
        v[j].z = __expf(v[j].z);
        v[j].w = __expf(v[j].w);
        s += (v[j].x + v[j].y) + (v[j].z + v[j].w);
        m = fmaxf(m, fmaxf(fmaxf(v[j].x, v[j].y), fmaxf(v[j].z, v[j].w)));
    }
    s = waveSum(s);
    const float inv = 1.0f / s;

    // Exact rare-row test: RN multiplication by positive inv/15 is monotone, so
    // max-of-predicate == predicate-of-max. rare <=> any element beyond bin 0.
    const bool rare = __any(m * inv * 15.0f > 1.0f);

    if (!rare) {
        // Common path: every element is bin 0. One mul + one ds_add each;
        // label correction is a single ds_add by the owning lane (label conf
        // is provably in bin 0 here, and conf > 0 for N(0,1) logits).
#pragma unroll
        for (int j = 0; j < 4; ++j) {
            unsafeAtomicAdd(&sB[0 * SBSTRIDE + 64 * j + lane], v[j].x * inv);
            unsafeAtomicAdd(&sB[1 * SBSTRIDE + 64 * j + lane], v[j].y * inv);
            unsafeAtomicAdd(&sB[2 * SBSTRIDE + 64 * j + lane], v[j].z * inv);
            unsafeAtomicAdd(&sB[3 * SBSTRIDE + 64 * j + lane], v[j].w * inv);
        }
        const int lq = label >> 2;            // quad index 0..249
        if (lane == (lq & 63))
            unsafeAtomicAdd(&sB[(label & 3) * SBSTRIDE + lq], -1.0f);
    } else {
        // Rare row (~85 in 65536): verified round-0 per-element logic.
#pragma unroll
        for (int j = 0; j < 4; ++j) {
            const int q = lane + 64 * j;
            const float cf[4] = {v[j].x, v[j].y, v[j].z, v[j].w};
#pragma unroll
            for (int k = 0; k < 4; ++k) {
                float conf = cf[k] * inv;
                float t    = conf * 15.0f;
                float add  = conf - ((4 * q + k == label) ? 1.0f : 0.0f);
                if (t > 1.0f) {
                    int b = min((int)ceilf(t) - 1, NBINS - 1);
                    unsafeAtomicAdd(&D[b * CDIM + k * QDIM + q], add);
                } else {
                    unsafeAtomicAdd(&sB[k * SBSTRIDE + q], add);   // pad q: add == 0
                }
            }
        }
    }
}

__global__ __launch_bounds__(THREADS, 8) void ece_hist_kernel(
        const float* __restrict__ logits,
        const int*   __restrict__ labels,
        float*       __restrict__ D,
        int N, int rowsPerBlock)
{
    __shared__ float sB[4 * SBSTRIDE];       // 4 KB padded bin-0 accumulator

    const int tid  = threadIdx.x;
    const int lane = tid & 63;
    const int w    = tid >> 6;               // wave id 0..15

    sB[tid & (4 * SBSTRIDE - 1)] = 0.0f;     // THREADS == 1024 == 4*SBSTRIDE
    __syncthreads();

    const int r0 = blockIdx.x * rowsPerBlock;
    const int r1 = min(r0 + rowsPerBlock, N);

    // Depth-2 ping-pong pipeline: while computing row i, row i+1 is in flight.
    // 32 buffer VGPRs total; latency hiding comes from 8 waves/SIMD (TLP).
    float4 vA[4], vB[4];
    int    lA = 0, lB = 0;

    int rA = r0 + w;                         // this wave's rows: rA, rA+16, ...
    int rB = rA + NWAVES;

    if (rA < r1) loadRow(vA, lA, logits, labels, rA, lane);

    while (rA < r1) {
        if (rB < r1) loadRow(vB, lB, logits, labels, rB, lane);
        computeRow(vA, lA, lane, sB, D);
        rA = rB + NWAVES;
        if (rA < r1) loadRow(vA, lA, logits, labels, rA, lane);

        if (rB >= r1) break;
        computeRow(vB, lB, lane, sB, D);
        rB = rA + NWAVES;
    }

    __syncthreads();
    // Flush bin-0 partials to global (1000 atomics per block).
    if (tid < CDIM) {
        const int k = tid / QDIM;            // magic-mul, once per block
        const int q = tid - k * QDIM;
        float val = sB[k * SBSTRIDE + q];
        if (val != 0.0f) unsafeAtomicAdd(&D[tid], val);
    }
}

__global__ __launch_bounds__(1024) void ece_final_kernel(
        const float* __restrict__ D, float* __restrict__ out, float scale)
{
    float s = 0.0f;
    const float4* D4 = (const float4*)D;     // HIST_ELEMS % 4 == 0
    for (int i = threadIdx.x; i < HIST_ELEMS / 4; i += 1024) {
        float4 t = D4[i];
        s += (fabsf(t.x) + fabsf(t.y)) + (fabsf(t.z) + fabsf(t.w));
    }
    s = waveSum(s);
    __shared__ float sr[16];
    const int lane = threadIdx.x & 63;
    const int wid  = threadIdx.x >> 6;
    if (lane == 0) sr[wid] = s;
    __syncthreads();
    if (threadIdx.x == 0) {
        float t = 0.0f;
#pragma unroll
        for (int ww = 0; ww < 16; ++ww) t += sr[ww];
        out[0] = t * scale;
    }
}

extern "C" void kernel_launch(void* const* d_in, const int* in_sizes, int n_in,
                              void* d_out, int out_size, void* d_ws, size_t ws_size,
                              hipStream_t stream)
{
    const float* logits = (const float*)d_in[0];
    const int*   labels = (const int*)d_in[1];

    const int N = in_sizes[1];                        // 65536 rows

    float* D = (float*)d_ws;
    hipMemsetAsync(D, 0, HIST_ELEMS * sizeof(float), stream);

    const int grid = 512;                             // 2 blocks/CU (2048 thr/CU)
    const int rowsPerBlock = (N + grid - 1) / grid;   // 128 -> 8 rows/wave

    ece_hist_kernel<<<grid, THREADS, 0, stream>>>(logits, labels, D, N, rowsPerBlock);

    const float scale = 1.0f / ((float)N * (float)CDIM);
    ece_final_kernel<<<1, 1024, 0, stream>>>(D, (float*)d_out, scale);
}

// Round 3
// 71.022 us; speedup vs baseline: 5.0304x; 5.0304x over previous
//
#include <hip/hip_runtime.h>
#include <math.h>

#define NBINS   15
#define CDIM    1000
#define QDIM    250                 // CDIM / 4
#define HIST_ELEMS (NBINS * CDIM)
#define THREADS 512
#define NWAVES  (THREADS / 64)      // 8 waves per block
#define PAD     -1000.0f            // exp(PAD) == 0 exactly -> conf == 0 -> add == 0

__device__ __forceinline__ float waveSum(float v) {
#pragma unroll
    for (int o = 32; o > 0; o >>= 1) v += __shfl_xor(v, o, 64);
    return v;
}

__device__ __forceinline__ void loadRow(float4 (&v)[4], int& label,
                                        const float* __restrict__ logits,
                                        const int* __restrict__ labels,
                                        int r, int lane) {
    const float4* row = (const float4*)(logits + (size_t)r * CDIM);
#pragma unroll
    for (int j = 0; j < 4; ++j) {
        int q = lane + 64 * j;
        v[j] = (q < QDIM) ? row[q] : make_float4(PAD, PAD, PAD, PAD);
    }
    label = labels[r];
}

// Hot path: exp pass (+1 v_max/elem), wave sum, rare-row test, then ONE fmaf
// per element. Label correction = single lane-guarded ds_add (-1.0) into sB
// (valid in common path: !rare => all conf <= 1/15 => label is bin 0).
// Rare rows (~85 of 65536) run the verified baseline per-element logic.
__device__ __forceinline__ void computeRow(float4 (&v)[4], int label, int lane,
                                           float (&regAcc)[4][4],
                                           float* __restrict__ sB,
                                           float* __restrict__ D) {
    float s = 0.0f, m = 0.0f;
#pragma unroll
    for (int j = 0; j < 4; ++j) {
        v[j].x = __expf(v[j].x);
        v[j].y = __expf(v[j].y);
        v[j].z = __expf(v[j].z);
        v[j].w = __expf(v[j].w);
        s += (v[j].x + v[j].y) + (v[j].z + v[j].w);
        m = fmaxf(m, fmaxf(fmaxf(v[j].x, v[j].y), fmaxf(v[j].z, v[j].w)));
    }
    s = waveSum(s);
    const float inv = 1.0f / s;

    // Exact: RN mul by positive inv / 15 is monotone, so max-of-predicate ==
    // predicate-of-max; expression shape matches the per-element test exactly.
    const float cmax = m * inv;
    const bool  rare = __any(cmax * 15.0f > 1.0f);

    if (!rare) {
        // Common path: every element lands in bin 0. One v_fmac each.
#pragma unroll
        for (int j = 0; j < 4; ++j) {
            regAcc[j][0] = fmaf(v[j].x, inv, regAcc[j][0]);
            regAcc[j][1] = fmaf(v[j].y, inv, regAcc[j][1]);
            regAcc[j][2] = fmaf(v[j].z, inv, regAcc[j][2]);
            regAcc[j][3] = fmaf(v[j].w, inv, regAcc[j][3]);
        }
        // Label correction: owning lane subtracts 1.0 in LDS (bin-0 slot).
        const int lq = label >> 2;           // quad index 0..249
        const int lk = label & 3;            // component
        if (lane == (lq & 63))
            unsafeAtomicAdd(&sB[lk * QDIM + lq], -1.0f);
    } else {
        // Rare row: full per-element bin logic (verified baseline code).
#pragma unroll
        for (int j = 0; j < 4; ++j) {
            const int q = lane + 64 * j;
            const float cf[4] = {v[j].x, v[j].y, v[j].z, v[j].w};
#pragma unroll
            for (int k = 0; k < 4; ++k) {
                float conf = cf[k] * inv;
                float t    = conf * 15.0f;
                float add  = conf - ((4 * q + k == label) ? 1.0f : 0.0f);
                if (t > 1.0f) {
                    int b = min((int)ceilf(t) - 1, NBINS - 1);
                    unsafeAtomicAdd(&D[b * CDIM + k * QDIM + q], add);
                } else {
                    regAcc[j][k] += add;
                }
            }
        }
    }
}

// Global D layout: index = b*CDIM + k*QDIM + q, class c = 4*q + k (bijective;
// the final sum of |D| is layout-invariant). sB mirrors the b == 0 plane.
__global__ __launch_bounds__(THREADS, 4) void ece_hist_kernel(
        const float* __restrict__ logits,
        const int*   __restrict__ labels,
        float*       __restrict__ D,
        int N, int rowsPerBlock)
{
    __shared__ float sB[CDIM];           // 4 KB: block-level bin-0 reduce

    const int tid  = threadIdx.x;
    const int lane = tid & 63;
    const int w    = tid >> 6;           // wave id 0..7

    for (int i = tid; i < CDIM; i += THREADS) sB[i] = 0.0f;
    __syncthreads();

    const int r0 = blockIdx.x * rowsPerBlock;
    const int r1 = min(r0 + rowsPerBlock, N);

    float regAcc[4][4];
#pragma unroll
    for (int j = 0; j < 4; ++j)
#pragma unroll
        for (int k = 0; k < 4; ++k) regAcc[j][k] = 0.0f;

    // --- explicit 3-buffer software pipeline (proven clean allocation):
    //     while computing row i, loads for rows i+1 and i+2 are in flight.
    //     All buffer indices static; all guards wave-uniform.
    float4 vA[4], vB[4], vC[4];
    int    lA = 0, lB = 0, lC = 0;

    int rA = r0 + w;                     // this wave's rows: rA, rA+8, rA+16, ...
    int rB = rA + NWAVES;
    int rC = rB + NWAVES;

    if (rA < r1) loadRow(vA, lA, logits, labels, rA, lane);
    if (rB < r1) loadRow(vB, lB, logits, labels, rB, lane);
    if (rC < r1) loadRow(vC, lC, logits, labels, rC, lane);

    while (rA < r1) {
        computeRow(vA, lA, lane, regAcc, sB, D);
        rA = rC + NWAVES;
        if (rA < r1) loadRow(vA, lA, logits, labels, rA, lane);

        if (rB >= r1) break;
        computeRow(vB, lB, lane, regAcc, sB, D);
        rB = rA + NWAVES;
        if (rB < r1) loadRow(vB, lB, logits, labels, rB, lane);

        if (rC >= r1) break;
        computeRow(vC, lC, lane, regAcc, sB, D);
        rC = rB + NWAVES;
        if (rC < r1) loadRow(vC, lC, logits, labels, rC, lane);
    }

    // Block-level reduce of bin-0 registers (once per block, native ds_add).
#pragma unroll
    for (int j = 0; j < 4; ++j) {
        int q = lane + 64 * j;
        if (q < QDIM) {
#pragma unroll
            for (int k = 0; k < 4; ++k)
                unsafeAtomicAdd(&sB[k * QDIM + q], regAcc[j][k]);
        }
    }

    __syncthreads();
    // Flush bin-0 partials to global (1000 atomics per block).
    for (int i = tid; i < CDIM; i += THREADS) {
        float val = sB[i];
        if (val != 0.0f) unsafeAtomicAdd(&D[i], val);
    }
}

__global__ __launch_bounds__(1024) void ece_final_kernel(
        const float* __restrict__ D, float* __restrict__ out, float scale)
{
    float s = 0.0f;
    const float4* D4 = (const float4*)D;     // HIST_ELEMS % 4 == 0
    for (int i = threadIdx.x; i < HIST_ELEMS / 4; i += 1024) {
        float4 t = D4[i];
        s += (fabsf(t.x) + fabsf(t.y)) + (fabsf(t.z) + fabsf(t.w));
    }
    s = waveSum(s);
    __shared__ float sr[16];
    const int lane = threadIdx.x & 63;
    const int wid  = threadIdx.x >> 6;
    if (lane == 0) sr[wid] = s;
    __syncthreads();
    if (threadIdx.x == 0) {
        float t = 0.0f;
#pragma unroll
        for (int ww = 0; ww < 16; ++ww) t += sr[ww];
        out[0] = t * scale;
    }
}

extern "C" void kernel_launch(void* const* d_in, const int* in_sizes, int n_in,
                              void* d_out, int out_size, void* d_ws, size_t ws_size,
                              hipStream_t stream)
{
    const float* logits = (const float*)d_in[0];
    const int*   labels = (const int*)d_in[1];

    const int N = in_sizes[1];                        // 65536 rows

    float* D = (float*)d_ws;
    hipMemsetAsync(D, 0, HIST_ELEMS * sizeof(float), stream);

    const int grid = 512;                             // 2 blocks/CU, 16 rows/wave
    const int rowsPerBlock = (N + grid - 1) / grid;   // 128

    ece_hist_kernel<<<grid, THREADS, 0, stream>>>(logits, labels, D, N, rowsPerBlock);

    const float scale = 1.0f / ((float)N * (float)CDIM);
    ece_final_kernel<<<1, 1024, 0, stream>>>(D, (float*)d_out, scale);
}